// Round 12
// baseline (195.379 us; speedup 1.0000x reference)
//
#include <hip/hip_runtime.h>
#include <hip/hip_bf16.h>
#include <math.h>

// Problem constants
#define Bq  2
#define Sq  2048
#define Hq  1024
#define Nq  16
#define HNq 64
#define Mq  (Bq*Sq)        // 4096 rows
#define H3q (3*Hq)         // 3072

#define LOG2E 1.44269504088896340736f

typedef __attribute__((ext_vector_type(8))) short           short8;
typedef __attribute__((ext_vector_type(4))) short           short4s;
typedef __attribute__((ext_vector_type(8))) unsigned short  ushortx8;
typedef __attribute__((ext_vector_type(4))) unsigned short  ushortx4;
typedef __attribute__((ext_vector_type(4))) float           floatx4;

__device__ __forceinline__ unsigned short f2bf(float f) {
    union { float f; unsigned int u; } x; x.f = f;
    unsigned int r = (x.u + 0x7fffu + ((x.u >> 16) & 1u)) >> 16;
    return (unsigned short)r;
}

// packed fp32x2 -> bf16x2 (v_cvt_pk_bf16_f32 on gfx950); a in low 16 bits
__device__ __forceinline__ unsigned int pkbf(float a, float b) {
    float2 t; t.x = a; t.y = b;
    __hip_bfloat162 h = __float22bfloat162_rn(t);
    union { __hip_bfloat162 h; unsigned int u; } c; c.h = h;
    return c.u;
}

__device__ __forceinline__ float bf2f(unsigned short v) {
    union { unsigned int u; float f; } x; x.u = (unsigned int)v << 16;
    return x.f;
}

// raw v_exp_f32 (D = 2^S0): ONE transcendental op (libm exp2f is a guarded
// ~10-op sequence without fast-math -- was the hidden VALU hog).
__device__ __forceinline__ float fexp2(float x) {
    float r;
    asm("v_exp_f32 %0, %1" : "=v"(r) : "v"(x));
    return r;
}

// async global->LDS, 16B per lane; LDS dest = wave-uniform base + lane*16
__device__ __forceinline__ void gload16(const unsigned short* g, unsigned short* l) {
    __builtin_amdgcn_global_load_lds(
        (__attribute__((address_space(1))) void*)(unsigned long long)(g),
        (__attribute__((address_space(3))) void*)(unsigned int)(unsigned long long)(l),
        16, 0, 0);
}

// LDS bank swizzle: granule' = granule ^ swz(row mod 16); 2-way max conflict
__device__ __forceinline__ int swz(int r) { return (r ^ (r >> 2)) & 3; }

// ---------------------------------------------------------------------------
// Fused fp32 -> bf16 cast for hidden | W_qkv | W_out + permuted e^mask table
// em2[((b*32+kt)*2+ks)*32 + quad*8 + hi*4 + r]
//   = exp(mask[b][kt*64 + (2ks+hi)*16 + quad*4 + r])
// ---------------------------------------------------------------------------
#define N_HID ((size_t)Mq * Hq)          // 4194304
#define N_HW  (N_HID + (size_t)H3q * Hq) // 7340032
#define N_ALL (N_HW + (size_t)Hq * Hq)   // 8388608
#define CVT_BLKS ((int)(N_ALL / 2048))   // 4096

__global__ __launch_bounds__(256) void cvt_all(
    const float* __restrict__ hidden, const float* __restrict__ wqkv,
    const float* __restrict__ wout, const float* __restrict__ mask,
    unsigned short* __restrict__ dst, unsigned short* __restrict__ em2)
{
    const int bid = blockIdx.x;
    if (bid >= CVT_BLKS) {
        // ---- permuted e^mask table (2 blocks, 4096 outputs)
        const int t0   = ((bid - CVT_BLKS) * 256 + threadIdx.x) * 8;
        const int b    = t0 >> 11;
        const int t2   = t0 & 2047;
        const int kt   = t2 >> 6;
        const int t3   = t2 & 63;
        const int ks   = t3 >> 5;
        const int quad = (t3 >> 3) & 3;
        const int kb   = kt * 64 + ks * 32 + quad * 4;
        const float* mp = mask + (size_t)b * Sq + kb;
        float4 m0 = *(const float4*)(mp);
        float4 m1 = *(const float4*)(mp + 16);
        union { unsigned int u[4]; ushortx8 s; } o;
        o.u[0] = pkbf(fexp2(m0.x * LOG2E), fexp2(m0.y * LOG2E));
        o.u[1] = pkbf(fexp2(m0.z * LOG2E), fexp2(m0.w * LOG2E));
        o.u[2] = pkbf(fexp2(m1.x * LOG2E), fexp2(m1.y * LOG2E));
        o.u[3] = pkbf(fexp2(m1.z * LOG2E), fexp2(m1.w * LOG2E));
        *(ushortx8*)(em2 + t0) = o.s;
        return;
    }
    size_t i = ((size_t)bid * 256 + threadIdx.x) * 8;
    const float* src;
    if (i < N_HID)      src = hidden + i;
    else if (i < N_HW)  src = wqkv + (i - N_HID);
    else                src = wout + (i - N_HW);
    float4 a = *(const float4*)(src);
    float4 b = *(const float4*)(src + 4);
    union { unsigned int u[4]; ushortx8 s; } o;
    o.u[0] = pkbf(a.x, a.y); o.u[1] = pkbf(a.z, a.w);
    o.u[2] = pkbf(b.x, b.y); o.u[3] = pkbf(b.z, b.w);
    *(ushortx8*)(dst + i) = o.s;
}

// ---------------------------------------------------------------------------
// GEMM1: 256x128 tile, BK=32, 8 waves (512 thr) each computing 64x64.
// Triple-buffered LDS, depth-2 prefetch, counted vmcnt(3).
// Outputs:
//   Qb [row][1024]  Q * 0.125*log2e (bf16), dense
//   KV5 INTERLEAVED packed tiles per (b,n): 32 tiles x 8192 shorts =
//     [K tile 4096 | V tile 4096]. K half PRE-SWIZZLED
//     [r 64][((d>>3)^(r&7))*8 + (d&7)]; V half fragment-packed (e^mask
//     folded). Attention DMA for both is a LINEAR lane*16B copy.
// ---------------------------------------------------------------------------
#define TM 128
#define TN 128
#define TK 32
#define G1M 256

__global__ __launch_bounds__(512) void gemm_mfma_qkv(
    const unsigned short* __restrict__ A, const unsigned short* __restrict__ Bw,
    const float* __restrict__ bias, const float* __restrict__ mask,
    unsigned short* __restrict__ Qb, unsigned short* __restrict__ KV5, int K)
{
    __shared__ unsigned short As[3][G1M][TK];   // 48 KB
    __shared__ unsigned short Bs[3][TN][TK];    // 24 KB

    const int tid = threadIdx.x;
    const int w = tid >> 6, lane = tid & 63;
    const int l15 = lane & 15, quad = lane >> 4;
    const int wr = (w & 3) * 64;
    const int wc = (w >> 2) * 64;
    const int row0 = blockIdx.y * G1M;
    const int col0 = blockIdx.x * TN;

    const int srow16 = lane >> 2;
    const int sgd    = lane & 3;
    const int sgsrc  = (sgd ^ swz(srow16)) * 8;

    floatx4 acc[4][4];
    #pragma unroll
    for (int i = 0; i < 4; i++)
        #pragma unroll
        for (int j = 0; j < 4; j++) acc[i][j] = (floatx4){0.f,0.f,0.f,0.f};

    const int aswz = swz(l15) * 8;
    const int NK = K / TK;

    // prologue: stage tiles 0,1 (A: 2 segs/wave, B: 1 seg/wave)
    #pragma unroll
    for (int t = 0; t < 2; t++) {
        #pragma unroll
        for (int c = 0; c < 2; c++) {
            int seg = w * 2 + c;
            int r = seg * 16 + srow16;
            gload16(A + (size_t)(row0 + r) * K + t * TK + sgsrc, &As[t][seg * 16][0]);
        }
        int rB = w * 16 + srow16;
        gload16(Bw + (size_t)(col0 + rB) * K + t * TK + sgsrc, &Bs[t][w * 16][0]);
    }

    #pragma unroll 1
    for (int k = 0; k < NK; ++k) {
        if (k + 1 < NK) asm volatile("s_waitcnt vmcnt(3)" ::: "memory");
        else            asm volatile("s_waitcnt vmcnt(0)" ::: "memory");
        __builtin_amdgcn_s_barrier();
        __builtin_amdgcn_sched_barrier(0);

        const int cur = k % 3;
        if (k + 2 < NK) {                                  // prefetch tile k+2
            const int nb  = (k + 2) % 3;
            const int k0n = (k + 2) * TK;
            #pragma unroll
            for (int c = 0; c < 2; c++) {
                int seg = w * 2 + c;
                int r = seg * 16 + srow16;
                gload16(A + (size_t)(row0 + r) * K + k0n + sgsrc, &As[nb][seg * 16][0]);
            }
            int rB = w * 16 + srow16;
            gload16(Bw + (size_t)(col0 + rB) * K + k0n + sgsrc, &Bs[nb][w * 16][0]);
        }
        __builtin_amdgcn_sched_barrier(0);

        short8 af[4], bf[4];
        #pragma unroll
        for (int i = 0; i < 4; i++)
            af[i] = *(const short8*)&As[cur][wr + i * 16 + l15][(quad * 8) ^ aswz];
        #pragma unroll
        for (int j = 0; j < 4; j++)
            bf[j] = *(const short8*)&Bs[cur][wc + j * 16 + l15][(quad * 8) ^ aswz];
        __builtin_amdgcn_s_setprio(1);
        #pragma unroll
        for (int i = 0; i < 4; i++)
            #pragma unroll
            for (int j = 0; j < 4; j++)
                acc[i][j] = __builtin_amdgcn_mfma_f32_16x16x32_bf16(af[i], bf[j], acc[i][j], 0, 0, 0);
        __builtin_amdgcn_s_setprio(0);
    }

    const int cls = col0 >> 10;    // 0=Q, 1=K, 2=V; uniform per block

    if (cls == 2) {
        #pragma unroll
        for (int i = 0; i < 4; i++) {
            const int rb = row0 + wr + i * 16 + quad * 4;
            const int b  = rb >> 11;
            const int s  = rb & (Sq - 1);
            const int kt32 = s >> 6;
            const int sw   = s & 63;
            const int kg   = sw >> 2;          // s&3 == 0 (rb % 4 == 0)
            const int ks   = kg >> 3;
            const int q2   = kg & 3;
            const int hi   = (kg >> 2) & 1;
            float expm[4];
            #pragma unroll
            for (int rr = 0; rr < 4; rr++)
                expm[rr] = fexp2(mask[(size_t)b * Sq + s + rr] * LOG2E);
            #pragma unroll
            for (int j = 0; j < 4; j++) {
                const int c  = col0 + wc + j * 16 + l15;
                const int c2 = c - 2 * Hq;           // n*64+d
                const int n  = c2 >> 6, d = c2 & 63;
                const int dt = d >> 4, dl = d & 15;
                const float bia = bias[c];
                ushortx4 o;
                #pragma unroll
                for (int rr = 0; rr < 4; rr++)
                    o[rr] = f2bf((acc[i][j][rr] + bia) * expm[rr]);
                const size_t off = (((size_t)(b * Nq + n) * 32 + kt32) << 13) + 4096
                                 + (size_t)((ks * 16 + dt * 4 + q2) * 128 + dl * 8 + hi * 4);
                *(ushortx4*)&KV5[off] = o;
            }
        }
    } else if (cls == 1) {
        // K half, pre-swizzled rows (verified image)
        #pragma unroll
        for (int i = 0; i < 4; i++) {
            const int rb = row0 + wr + i * 16 + quad * 4;
            #pragma unroll
            for (int j = 0; j < 4; j++) {
                const int c  = col0 + wc + j * 16 + l15;
                const int c2 = c - Hq;               // n*64+d
                const int n  = c2 >> 6, d = c2 & 63;
                const float bia = bias[c];
                #pragma unroll
                for (int rr = 0; rr < 4; rr++) {
                    const int srow = rb + rr;
                    const int b    = srow >> 11;
                    const int s    = srow & (Sq - 1);
                    const int kt32 = s >> 6;
                    const int r    = s & 63;
                    const size_t off = (((size_t)(b * Nq + n) * 32 + kt32) << 13)
                                     + (size_t)(r * 64 + (((d >> 3) ^ (r & 7)) * 8 + (d & 7)));
                    KV5[off] = f2bf(acc[i][j][rr] + bia);
                }
            }
        }
    } else {
        const float qs = 0.125f * LOG2E;
        #pragma unroll
        for (int i = 0; i < 4; i++) {
            const int rb = row0 + wr + i * 16 + quad * 4;
            #pragma unroll
            for (int j = 0; j < 4; j++) {
                const int c = col0 + wc + j * 16 + l15;
                const float bia = bias[c];
                #pragma unroll
                for (int rr = 0; rr < 4; rr++)
                    Qb[(size_t)(rb + rr) * Hq + c] =
                        f2bf((acc[i][j][rr] + bia) * qs);
            }
        }
    }
}

// ---------------------------------------------------------------------------
// GEMM2: x = A*Bw^T + bias + residual -> bf16. 64x128 tile, 512 blocks
// (round-10 config, banked). Triple-buffered, depth-2, counted vmcnt(3).
// ---------------------------------------------------------------------------
#define T2M 64
#define T2N 128

__global__ __launch_bounds__(256) void gemm_mfma_out(
    const unsigned short* __restrict__ A, const unsigned short* __restrict__ Bw,
    const float* __restrict__ bias, const float* __restrict__ res,
    unsigned short* __restrict__ X, int M, int Nd, int K)
{
    __shared__ unsigned short As[3][T2M][TK];   // 12 KB
    __shared__ unsigned short Bs[3][T2N][TK];   // 24 KB

    const int tid = threadIdx.x;
    const int w = tid >> 6, lane = tid & 63;
    const int l15 = lane & 15, quad = lane >> 4;
    const int wr = (w & 1) * 32;
    const int wc = (w >> 1) * 64;
    const int row0 = blockIdx.y * T2M;
    const int col0 = blockIdx.x * T2N;

    const int srow16 = lane >> 2;
    const int sgd    = lane & 3;
    const int sgsrc  = (sgd ^ swz(srow16)) * 8;

    floatx4 acc[2][4];
    #pragma unroll
    for (int i = 0; i < 2; i++)
        #pragma unroll
        for (int j = 0; j < 4; j++) acc[i][j] = (floatx4){0.f,0.f,0.f,0.f};

    const int aswz = swz(l15) * 8;
    const int NK = K / TK;

    #pragma unroll
    for (int t = 0; t < 2; t++) {
        int rA = w * 16 + srow16;
        gload16(A + (size_t)(row0 + rA) * K + t * TK + sgsrc, &As[t][w * 16][0]);
        #pragma unroll
        for (int c = 0; c < 2; c++) {
            int seg = w * 2 + c;
            int rB = seg * 16 + srow16;
            gload16(Bw + (size_t)(col0 + rB) * K + t * TK + sgsrc, &Bs[t][seg * 16][0]);
        }
    }

    #pragma unroll 1
    for (int k = 0; k < NK; ++k) {
        if (k + 1 < NK) asm volatile("s_waitcnt vmcnt(3)" ::: "memory");
        else            asm volatile("s_waitcnt vmcnt(0)" ::: "memory");
        __builtin_amdgcn_s_barrier();
        __builtin_amdgcn_sched_barrier(0);

        const int cur = k % 3;
        if (k + 2 < NK) {
            const int nb  = (k + 2) % 3;
            const int k0n = (k + 2) * TK;
            int rA = w * 16 + srow16;
            gload16(A + (size_t)(row0 + rA) * K + k0n + sgsrc, &As[nb][w * 16][0]);
            #pragma unroll
            for (int c = 0; c < 2; c++) {
                int seg = w * 2 + c;
                int rB = seg * 16 + srow16;
                gload16(Bw + (size_t)(col0 + rB) * K + k0n + sgsrc, &Bs[nb][seg * 16][0]);
            }
        }
        __builtin_amdgcn_sched_barrier(0);

        short8 af[2], bf[4];
        #pragma unroll
        for (int i = 0; i < 2; i++)
            af[i] = *(const short8*)&As[cur][wr + i * 16 + l15][(quad * 8) ^ aswz];
        #pragma unroll
        for (int j = 0; j < 4; j++)
            bf[j] = *(const short8*)&Bs[cur][wc + j * 16 + l15][(quad * 8) ^ aswz];
        __builtin_amdgcn_s_setprio(1);
        #pragma unroll
        for (int i = 0; i < 2; i++)
            #pragma unroll
            for (int j = 0; j < 4; j++)
                acc[i][j] = __builtin_amdgcn_mfma_f32_16x16x32_bf16(af[i], bf[j], acc[i][j], 0, 0, 0);
        __builtin_amdgcn_s_setprio(0);
    }

    #pragma unroll
    for (int i = 0; i < 2; i++) {
        const int rb = row0 + wr + i * 16 + quad * 4;
        #pragma unroll
        for (int j = 0; j < 4; j++) {
            const int c = col0 + wc + j * 16 + l15;
            const float bia = bias[c];
            #pragma unroll
            for (int rr = 0; rr < 4; rr++) {
                X[(size_t)(rb + rr) * Nd + c] =
                    f2bf(acc[i][j][rr] + bia + res[(size_t)(rb + rr) * Nd + c]);
            }
        }
    }
}

// ---------------------------------------------------------------------------
// Full-K (z=1) flash attention, XCD-clustered, KV-interleaved, now with
// DEPTH-2 KV prefetch + COUNTED vmcnt(4) (T3/T4): each KV tile has TWO full
// compute bodies of latency cover, and the per-tile wait keeps the next
// tile's 4 loads in flight across the barrier (never drains to 0 mid-loop).
// mf loads are issued BEFORE the KV DMAs so the explicit vmcnt(4) drains
// them without touching the prefetch (vmcnt retires in order).
// Rings: K 3 buffers (kt, kt+1, kt+2), V 4 buffers (PV reads kt-1 while
// kt+2 is being issued; distance 3 is coprime with 4 => no overlap; the
// (kt+2)%3==(kt-1)%3 K reuse is freed at the preceding barrier).
// LDS 24+32 = 56 KB (2 blocks/CU unchanged; grid=512 is the residency cap).
// ---------------------------------------------------------------------------
#define KTILES 32   // 64-key tiles, full sequence

__device__ __forceinline__ floatx4 mfma16(short8 a, short8 b, floatx4 c) {
    return __builtin_amdgcn_mfma_f32_16x16x32_bf16(a, b, c, 0, 0, 0);
}

// l-MFMA + PV for the PREVIOUS tile; V fragments read from LDS (Vt = tile
// base + lane*8, conflict-free b128 at stride 1024B)
__device__ __forceinline__ void do_lpv(
    const short8 (&pf0)[2], const short8 (&pf1)[2], const short8 (&mf)[2],
    const unsigned short* Vt,
    floatx4 (&oacc0)[4], floatx4 (&oacc1)[4],
    floatx4 &lacc0, floatx4 &lacc1)
{
    __builtin_amdgcn_s_setprio(1);
    lacc0 = mfma16(mf[0], pf0[0], lacc0);
    lacc0 = mfma16(mf[1], pf0[1], lacc0);
    lacc1 = mfma16(mf[0], pf1[0], lacc1);
    lacc1 = mfma16(mf[1], pf1[1], lacc1);
    #pragma unroll
    for (int dt = 0; dt < 4; dt++) {
        short8 vlo = *(const short8*)(Vt + dt * 512);
        short8 vhi = *(const short8*)(Vt + 2048 + dt * 512);
        oacc0[dt] = mfma16(vlo, pf0[0], oacc0[dt]);
        oacc1[dt] = mfma16(vlo, pf1[0], oacc1[dt]);
        oacc0[dt] = mfma16(vhi, pf0[1], oacc0[dt]);
        oacc1[dt] = mfma16(vhi, pf1[1], oacc1[dt]);
    }
    __builtin_amdgcn_s_setprio(0);
}

template<bool HAVER, bool PREF2, int VW>
__device__ __forceinline__ void attn_body(
    int kt,
    unsigned short (&KsL)[3][64][64],
    unsigned short (&VsL)[4][4096],
    const unsigned short* KVb, const unsigned short* e2b,
    int w, int l15, int quad, int lane,
    const short8 (&qf0)[2], const short8 (&qf1)[2],
    const short8 (&pfR0)[2], const short8 (&pfR1)[2], const short8 (&mfR)[2],
    short8 (&pfW0)[2], short8 (&pfW1)[2], short8 (&mfW)[2],
    floatx4 (&oacc0)[4], floatx4 (&oacc1)[4],
    floatx4 &lacc0, floatx4 &lacc1)
{
    // counted wait: drains KV(kt) (+ the older mf), keeps KV(kt+1) in flight
    asm volatile("s_waitcnt vmcnt(%0)" :: "i"(VW) : "memory");
    __builtin_amdgcn_s_barrier();
    __builtin_amdgcn_sched_barrier(0);

    // mf for THIS tile FIRST (older than the new DMAs => next body's
    // vmcnt(4) drains it without draining the prefetch)
    const unsigned short* ep = e2b + kt * 64;
    mfW[0] = *(const short8*)(ep + quad * 8);
    mfW[1] = *(const short8*)(ep + 32 + quad * 8);
    __builtin_amdgcn_sched_barrier(0);

    if (PREF2) {
        // KV(kt+2): linear lane copies of one contiguous 16KB tile
        const unsigned short* tb = KVb + (size_t)(kt + 2) * 8192 + w * 1024 + lane * 8;
        gload16(tb,       &KsL[(kt + 2) % 3][w * 16][0]);
        gload16(tb + 512, &KsL[(kt + 2) % 3][w * 16 + 8][0]);
        unsigned short* vd = &VsL[(kt + 2) & 3][w * 1024];
        gload16(tb + 4096,       vd);
        gload16(tb + 4096 + 512, vd + 512);
    }
    __builtin_amdgcn_sched_barrier(0);   // pin DMAs as oldest outstanding

    // ---- QK(kt): S^T = K Q^T for both subtiles
    floatx4 s0[4], s1[4];
    #pragma unroll
    for (int ct = 0; ct < 4; ct++) {
        s0[ct] = (floatx4){0.f,0.f,0.f,0.f};
        s1[ct] = (floatx4){0.f,0.f,0.f,0.f};
    }
    __builtin_amdgcn_s_setprio(1);
    #pragma unroll
    for (int ks = 0; ks < 2; ks++) {
        #pragma unroll
        for (int ct = 0; ct < 4; ct++) {
            short8 af = *(const short8*)&KsL[kt % 3][ct * 16 + l15][((4 * ks + quad) ^ (l15 & 7)) * 8];
            s0[ct] = mfma16(af, qf0[ks], s0[ct]);
            s1[ct] = mfma16(af, qf1[ks], s1[ct]);
        }
    }
    __builtin_amdgcn_s_setprio(0);

    // ---- softmax(kt) -> pfW (exp2-only via raw v_exp_f32; mask in V'/mf)
    #pragma unroll
    for (int ks = 0; ks < 2; ks++) {
        union { unsigned int u[4]; short8 s; } pk;
        #pragma unroll
        for (int h = 0; h < 2; h++) {
            const int ct = ks * 2 + h;
            pk.u[h * 2]     = pkbf(fexp2(s0[ct][0]), fexp2(s0[ct][1]));
            pk.u[h * 2 + 1] = pkbf(fexp2(s0[ct][2]), fexp2(s0[ct][3]));
        }
        pfW0[ks] = pk.s;
    }
    #pragma unroll
    for (int ks = 0; ks < 2; ks++) {
        union { unsigned int u[4]; short8 s; } pk;
        #pragma unroll
        for (int h = 0; h < 2; h++) {
            const int ct = ks * 2 + h;
            pk.u[h * 2]     = pkbf(fexp2(s1[ct][0]), fexp2(s1[ct][1]));
            pk.u[h * 2 + 1] = pkbf(fexp2(s1[ct][2]), fexp2(s1[ct][3]));
        }
        pfW1[ks] = pk.s;
    }

    // ---- l + PV for tile kt-1 from LDS (overlaps the exp2 chain above)
    if (HAVER)
        do_lpv(pfR0, pfR1, mfR, &VsL[(kt + 3) & 3][0] + lane * 8,
               oacc0, oacc1, lacc0, lacc1);
}

__global__ __launch_bounds__(256) void attn_mfma(
    const unsigned short* __restrict__ Qb, const unsigned short* __restrict__ KV5,
    const unsigned short* __restrict__ em2, unsigned short* __restrict__ ctx)
{
    __shared__ unsigned short Ks[3][64][64];   // 24 KB, triple-buffered
    __shared__ unsigned short Vs[4][4096];     // 32 KB, quad-buffered

    const int tid  = threadIdx.x;
    const int w    = tid >> 6;
    const int lane = tid & 63;
    const int l15  = lane & 15;
    const int quad = lane >> 4;

    // XCD-clustering decode: all 16 qtiles of group g=bn share K/V and land
    // on XCD g%8 (dispatch round-robins linear id across 8 XCDs). 512 blocks.
    const int i_    = blockIdx.x;
    const int gl8   = i_ & 7;
    const int rest  = i_ >> 3;
    const int qtile = rest & 15;               // 0..15 (128 queries each)
    const int g     = (rest >> 4) * 8 + gl8;   // 0..31 = bn
    const int n     = g & 15;
    const int b     = g >> 4;

    // Q B-fragments for both subtiles (n=l15 -> query row, k=quad*8+j)
    short8 qf0[2], qf1[2];
    {
        const int qrow0 = qtile * 128 + w * 16 + l15;
        const unsigned short* qp = Qb + (size_t)(b * Sq + qrow0) * Hq + n * HNq + quad * 8;
        qf0[0] = *(const short8*)(qp);
        qf0[1] = *(const short8*)(qp + 32);
        qp += (size_t)64 * Hq;
        qf1[0] = *(const short8*)(qp);
        qf1[1] = *(const short8*)(qp + 32);
    }

    floatx4 oacc0[4], oacc1[4];   // O^T per subtile: d = dt*16+quad*4+r, q=l15
    #pragma unroll
    for (int dt = 0; dt < 4; dt++) {
        oacc0[dt] = (floatx4){0.f,0.f,0.f,0.f};
        oacc1[dt] = (floatx4){0.f,0.f,0.f,0.f};
    }
    floatx4 lacc0 = (floatx4){0.f,0.f,0.f,0.f};
    floatx4 lacc1 = (floatx4){0.f,0.f,0.f,0.f};

    // interleaved KV tile base + permuted mask base
    const unsigned short* KVb = KV5 + (size_t)(b * Nq + n) * 32 * 8192;
    const unsigned short* e2b = em2 + (size_t)b * 32 * 64;

    // prologue: KV(0) -> bufs 0, KV(1) -> bufs 1 (linear lane copies)
    #pragma unroll
    for (int t = 0; t < 2; t++) {
        const unsigned short* tb = KVb + (size_t)t * 8192 + w * 1024 + lane * 8;
        gload16(tb,        &Ks[t][w * 16][0]);
        gload16(tb + 512,  &Ks[t][w * 16 + 8][0]);
        gload16(tb + 4096,       &Vs[t][w * 1024]);
        gload16(tb + 4096 + 512, &Vs[t][w * 1024] + 512);
    }

    // pipeline state (two named stages, no dynamic indexing)
    short8 pfA0[2], pfA1[2], mfA[2];
    short8 pfB0[2], pfB1[2], mfB[2];

    // peel kt=0: fills stage A; no PV yet
    attn_body<false, true, 4>(0, Ks, Vs, KVb, e2b, w, l15, quad, lane,
        qf0, qf1, pfB0, pfB1, mfB, pfA0, pfA1, mfA, oacc0, oacc1, lacc0, lacc1);

    #pragma unroll 1
    for (int kt = 1; kt < KTILES - 3; kt += 2) {   // kt = 1,3,...,27
        attn_body<true, true, 4>(kt, Ks, Vs, KVb, e2b, w, l15, quad, lane,
            qf0, qf1, pfA0, pfA1, mfA, pfB0, pfB1, mfB, oacc0, oacc1, lacc0, lacc1);
        attn_body<true, true, 4>(kt + 1, Ks, Vs, KVb, e2b, w, l15, quad, lane,
            qf0, qf1, pfB0, pfB1, mfB, pfA0, pfA1, mfA, oacc0, oacc1, lacc0, lacc1);
    }
    // tail: kt=29 (last with prefetch), 30, 31
    attn_body<true, true, 4>(KTILES - 3, Ks, Vs, KVb, e2b, w, l15, quad, lane,
        qf0, qf1, pfA0, pfA1, mfA, pfB0, pfB1, mfB, oacc0, oacc1, lacc0, lacc1);
    attn_body<true, false, 4>(KTILES - 2, Ks, Vs, KVb, e2b, w, l15, quad, lane,
        qf0, qf1, pfB0, pfB1, mfB, pfA0, pfA1, mfA, oacc0, oacc1, lacc0, lacc1);
    attn_body<true, false, 0>(KTILES - 1, Ks, Vs, KVb, e2b, w, l15, quad, lane,
        qf0, qf1, pfA0, pfA1, mfA, pfB0, pfB1, mfB, oacc0, oacc1, lacc0, lacc1);
    // drain: l + PV of tile 31 (stage B, V(31) in Vs[31%4 = 3])
    do_lpv(pfB0, pfB1, mfB, &Vs[(KTILES - 1) & 3][0] + lane * 8,
           oacc0, oacc1, lacc0, lacc1);

    // ---- epilogue: l is COMPLETE (z=1) -> normalize in fp32, write ctx
    #pragma unroll
    for (int sub = 0; sub < 2; sub++) {
        const float inv = 1.0f / (sub ? lacc1[0] : lacc0[0]);
        const int qrow = qtile * 128 + sub * 64 + w * 16 + l15;
        #pragma unroll
        for (int dt = 0; dt < 4; dt++) {
            const floatx4 oa = sub ? oacc1[dt] : oacc0[dt];
            union { unsigned int u[2]; ushortx4 s; } o;
            o.u[0] = pkbf(oa[0] * inv, oa[1] * inv);
            o.u[1] = pkbf(oa[2] * inv, oa[3] * inv);
            const int col = n * HNq + dt * 16 + quad * 4;
            *(ushortx4*)&ctx[(size_t)(b * Sq + qrow) * Hq + col] = o.s;
        }
    }
}

// ---------------------------------------------------------------------------
// Row LayerNorm over H=1024, bf16 input, fp32 stats, fp32 output.
// ---------------------------------------------------------------------------
__global__ __launch_bounds__(256) void ln_kernel(
    const unsigned short* __restrict__ X, const float* __restrict__ gamma,
    const float* __restrict__ beta, float* __restrict__ out)
{
    const int row = blockIdx.x;
    const int c0  = threadIdx.x * 4;
    ushortx4 xv = *(const ushortx4*)(X + (size_t)row * Hq + c0);
    float vals[4];
    float lsum = 0.0f;
    #pragma unroll
    for (int i = 0; i < 4; i++) { vals[i] = bf2f(xv[i]); lsum += vals[i]; }

    __shared__ float red[8];
    const int wid = threadIdx.x >> 6, lane = threadIdx.x & 63;

    float s = lsum;
    #pragma unroll
    for (int off = 32; off >= 1; off >>= 1) s += __shfl_xor(s, off, 64);
    if (lane == 0) red[wid] = s;
    __syncthreads();
    const float mean = (red[0] + red[1] + red[2] + red[3]) * (1.0f / Hq);

    float v = 0.0f;
    #pragma unroll
    for (int i = 0; i < 4; i++) { float d = vals[i] - mean; v += d * d; }
    #pragma unroll
    for (int off = 32; off >= 1; off >>= 1) v += __shfl_xor(v, off, 64);
    if (lane == 0) red[4 + wid] = v;
    __syncthreads();
    const float var  = (red[4] + red[5] + red[6] + red[7]) * (1.0f / Hq);
    const float rstd = rsqrtf(var + 1e-12f);

    float4 gm = *(const float4*)(gamma + c0);
    float4 bt = *(const float4*)(beta + c0);
    float4 o;
    o.x = (vals[0] - mean) * rstd * gm.x + bt.x;
    o.y = (vals[1] - mean) * rstd * gm.y + bt.y;
    o.z = (vals[2] - mean) * rstd * gm.z + bt.z;
    o.w = (vals[3] - mean) * rstd * gm.w + bt.w;
    *(float4*)(out + (size_t)row * Hq + c0) = o;
}

// ---------------------------------------------------------------------------
// Workspace (56 MB): hidden_bf | Wqkv_bf | Wout_bf | Qb | KV5(8M) | ctx |
// x_bf | em2. Five kernels.
// ---------------------------------------------------------------------------
extern "C" void kernel_launch(void* const* d_in, const int* in_sizes, int n_in,
                              void* d_out, int out_size, void* d_ws, size_t ws_size,
                              hipStream_t stream)
{
    const float* hidden = (const float*)d_in[0];
    const float* mask   = (const float*)d_in[1];
    const float* W_qkv  = (const float*)d_in[2];
    const float* b_qkv  = (const float*)d_in[3];
    const float* W_out  = (const float*)d_in[4];
    const float* b_out  = (const float*)d_in[5];
    const float* gamma  = (const float*)d_in[6];
    const float* beta   = (const float*)d_in[7];
    float* out = (float*)d_out;

    const size_t nHid  = (size_t)Mq * Hq;        // 4 M
    const size_t nWq   = (size_t)H3q * Hq;       // 3 M
    const size_t nWo   = (size_t)Hq * Hq;        // 1 M

    unsigned short* hidden_bf = (unsigned short*)d_ws;
    unsigned short* Wqkv_bf   = hidden_bf + nHid;
    unsigned short* Wout_bf   = Wqkv_bf + nWq;
    unsigned short* qb        = Wout_bf + nWo;          // Q  [4096][1024]
    unsigned short* kv5       = qb + nHid;              // interleaved K|V, 8 M
    unsigned short* ctx_bf    = kv5 + 2 * nHid;
    unsigned short* x_bf      = ctx_bf + nHid;
    unsigned short* em2       = x_bf + nHid;            // 8 KB

    dim3 blk(256);

    // 0) fused fp32 -> bf16 cast + permuted expmask table (one kernel)
    cvt_all<<<dim3(CVT_BLKS + 2), blk, 0, stream>>>(
        hidden, W_qkv, W_out, mask, hidden_bf, em2);

    // 1) QKV projection (MFMA, 256x128 tile, depth-2) -> Qb / KV5
    gemm_mfma_qkv<<<dim3(H3q / TN, Mq / G1M), dim3(512), 0, stream>>>(
        hidden_bf, Wqkv_bf, b_qkv, mask, qb, kv5, Hq);

    // 2) Full-K flash attention (depth-2 KV prefetch, counted vmcnt) -> ctx
    attn_mfma<<<dim3(512), blk, 0, stream>>>(
        qb, kv5, em2, ctx_bf);

    // 3) Output projection (MFMA, 64x128 tile, 512 blocks) + residual -> x bf16
    gemm_mfma_out<<<dim3(Hq / T2N, Mq / T2M), blk, 0, stream>>>(
        ctx_bf, Wout_bf, b_out, hidden, x_bf, Mq, Hq, Hq);

    // 4) LayerNorm: bf16 x -> fp32 out
    ln_kernel<<<dim3(Mq), blk, 0, stream>>>(x_bf, gamma, beta, out);
}